// Round 6
// baseline (122.565 us; speedup 1.0000x reference)
//
#include <hip/hip_runtime.h>

#define DH 512
#define NB 2048
#define BLOCK 256
#define EPS 1e-6f

// d_ws layout: [0, NB) float partials | at byte offset NB*4: uint32 counter
// counter is zeroed by hipMemsetAsync each launch (graph-capturable).

__global__ __launch_bounds__(BLOCK) void siamese_fused(
    const float* __restrict__ x1, const float* __restrict__ x2,
    const float* __restrict__ y1, const float* __restrict__ y2,
    const float* __restrict__ yp1, float* partial, unsigned* counter,
    float* __restrict__ out, int B)
{
    const int lane = threadIdx.x & 63;
    const int wib  = threadIdx.x >> 6;                       // wave in block
    const int wid  = blockIdx.x * (BLOCK >> 6) + wib;        // global wave id
    const int nw   = gridDim.x * (BLOCK >> 6);               // total waves

    float acc = 0.0f;

    for (int r0 = wid * 2; r0 < B; r0 += nw * 2) {
        const int r1 = r0 + 1;                               // B even
        const size_t base0 = (size_t)r0 * DH;
        const size_t base1 = (size_t)r1 * DH;
        const float4* pa0 = reinterpret_cast<const float4*>(x1 + base0) + lane * 2;
        const float4* pb0 = reinterpret_cast<const float4*>(x2 + base0) + lane * 2;
        const float4* pa1 = reinterpret_cast<const float4*>(x1 + base1) + lane * 2;
        const float4* pb1 = reinterpret_cast<const float4*>(x2 + base1) + lane * 2;

        float4 a00 = pa0[0], a01 = pa0[1];
        float4 b00 = pb0[0], b01 = pb0[1];
        float4 a10 = pa1[0], a11 = pa1[1];
        float4 b10 = pb1[0], b11 = pb1[1];

        float ssq0 = 0.0f, ssq1 = 0.0f;
        float d;
        d = a00.x - b00.x; ssq0 = fmaf(d, d, ssq0);
        d = a00.y - b00.y; ssq0 = fmaf(d, d, ssq0);
        d = a00.z - b00.z; ssq0 = fmaf(d, d, ssq0);
        d = a00.w - b00.w; ssq0 = fmaf(d, d, ssq0);
        d = a01.x - b01.x; ssq0 = fmaf(d, d, ssq0);
        d = a01.y - b01.y; ssq0 = fmaf(d, d, ssq0);
        d = a01.z - b01.z; ssq0 = fmaf(d, d, ssq0);
        d = a01.w - b01.w; ssq0 = fmaf(d, d, ssq0);
        d = a10.x - b10.x; ssq1 = fmaf(d, d, ssq1);
        d = a10.y - b10.y; ssq1 = fmaf(d, d, ssq1);
        d = a10.z - b10.z; ssq1 = fmaf(d, d, ssq1);
        d = a10.w - b10.w; ssq1 = fmaf(d, d, ssq1);
        d = a11.x - b11.x; ssq1 = fmaf(d, d, ssq1);
        d = a11.y - b11.y; ssq1 = fmaf(d, d, ssq1);
        d = a11.z - b11.z; ssq1 = fmaf(d, d, ssq1);
        d = a11.w - b11.w; ssq1 = fmaf(d, d, ssq1);

        #pragma unroll
        for (int off = 32; off > 0; off >>= 1) {
            ssq0 += __shfl_xor(ssq0, off);
            ssq1 += __shfl_xor(ssq1, off);
        }

        // epilogue: lanes 0 and 1 handle one row each.
        // exact-equality branch: rows equal <=> ssq == 0 exactly.
        if (lane < 2) {
            const int   row = (lane == 0) ? r0   : r1;
            const float ssq = (lane == 0) ? ssq0 : ssq1;
            float dx = sqrtf(ssq + EPS);
            float2 v1 = *reinterpret_cast<const float2*>(y1  + (size_t)row * 2);
            float2 v2 = *reinterpret_cast<const float2*>(y2  + (size_t)row * 2);
            float2 vp = *reinterpret_cast<const float2*>(yp1 + (size_t)row * 2);
            float e0 = v1.x - v2.x, e1 = v1.y - v2.y;
            float dy = sqrtf(fmaf(e0, e0, fmaf(e1, e1, EPS)));
            float w  = (ssq == 0.0f) ? 1.0f : dx;
            float t  = dx - dy;
            float g0 = v1.x - vp.x, g1 = v1.y - vp.y;
            acc += t * t / w + g0 * g0 + g1 * g1;
        }
    }

    // per-wave reduce of acc
    #pragma unroll
    for (int off = 32; off > 0; off >>= 1)
        acc += __shfl_xor(acc, off);

    __shared__ float s[BLOCK >> 6];
    __shared__ int s_last;
    if (lane == 0) s[wib] = acc;
    __syncthreads();

    if (threadIdx.x == 0) {
        float t = 0.0f;
        #pragma unroll
        for (int i = 0; i < (BLOCK >> 6); ++i) t += s[i];
        partial[blockIdx.x] = t;        // publish block partial
        __threadfence();                // release: make visible device-wide
        unsigned old = atomicAdd(counter, 1u);
        s_last = (old == (unsigned)(gridDim.x - 1));
    }
    __syncthreads();

    if (s_last) {
        __threadfence();                // acquire: invalidate stale caches
        float a = 0.0f;
        for (int i = threadIdx.x; i < NB; i += BLOCK) a += partial[i];
        #pragma unroll
        for (int off = 32; off > 0; off >>= 1)
            a += __shfl_xor(a, off);
        if (lane == 0) s[wib] = a;
        __syncthreads();
        if (threadIdx.x == 0) {
            float t = 0.0f;
            #pragma unroll
            for (int i = 0; i < (BLOCK >> 6); ++i) t += s[i];
            out[0] = t;                 // overwrite, never accumulate
        }
    }
}

extern "C" void kernel_launch(void* const* d_in, const int* in_sizes, int n_in,
                              void* d_out, int out_size, void* d_ws, size_t ws_size,
                              hipStream_t stream) {
    const float* x1  = (const float*)d_in[0];
    const float* x2  = (const float*)d_in[1];
    const float* y1  = (const float*)d_in[2];
    const float* y2  = (const float*)d_in[3];
    const float* yp1 = (const float*)d_in[4];
    float* out = (float*)d_out;
    float*    partial = (float*)d_ws;                       // NB floats
    unsigned* counter = (unsigned*)((char*)d_ws + NB * 4);  // 1 uint

    const int B = in_sizes[0] / DH;         // 65536

    // d_ws is poisoned 0xAA once before timing and never re-poisoned:
    // zero the arrival counter every launch (async memset is capturable).
    hipMemsetAsync(counter, 0, sizeof(unsigned), stream);

    siamese_fused<<<NB, BLOCK, 0, stream>>>(x1, x2, y1, y2, yp1,
                                            partial, counter, out, B);
}

// Round 7
// 46.012 us; speedup vs baseline: 2.6638x; 2.6638x over previous
//
#include <hip/hip_runtime.h>

#define DH 512
#define NB 2048
#define BLOCK 256
#define EPS 1e-6f

__global__ __launch_bounds__(BLOCK) void siamese_partial(
    const float* __restrict__ x1, const float* __restrict__ x2,
    const float* __restrict__ y1, const float* __restrict__ y2,
    const float* __restrict__ yp1, float* __restrict__ partial, int B)
{
    const int lane = threadIdx.x & 63;
    const int wib  = threadIdx.x >> 6;                       // wave in block
    const int wid  = blockIdx.x * (BLOCK >> 6) + wib;        // global wave id
    const int nw   = gridDim.x * (BLOCK >> 6);               // total waves

    const int P   = B >> 1;                                  // row pairs
    const int ppw = P / nw;                                  // pairs per wave (4)
    // contiguous assignment: wave owns pairs [wid*ppw, (wid+1)*ppw)
    // -> 16 KB contiguous per array per wave (DRAM row-buffer locality)
    const int p0 = wid * ppw;
    const int p1 = (p0 + ppw < P) ? p0 + ppw : P;

    float acc = 0.0f;

    for (int p = p0; p < p1; ++p) {
        const size_t base = (size_t)p * (2 * DH);
        const float4* q1 = reinterpret_cast<const float4*>(x1 + base) + lane * 2;
        const float4* q2 = reinterpret_cast<const float4*>(x2 + base) + lane * 2;

        // 8 loads up front (row r0 = 2p at offset 0, row r1 = 2p+1 at +128 f4)
        float4 a00 = q1[0],   a01 = q1[1];
        float4 b00 = q2[0],   b01 = q2[1];
        float4 a10 = q1[128], a11 = q1[129];
        float4 b10 = q2[128], b11 = q2[129];

        float ssq0 = 0.0f, ssq1 = 0.0f;
        float d;
        d = a00.x - b00.x; ssq0 = fmaf(d, d, ssq0);
        d = a00.y - b00.y; ssq0 = fmaf(d, d, ssq0);
        d = a00.z - b00.z; ssq0 = fmaf(d, d, ssq0);
        d = a00.w - b00.w; ssq0 = fmaf(d, d, ssq0);
        d = a01.x - b01.x; ssq0 = fmaf(d, d, ssq0);
        d = a01.y - b01.y; ssq0 = fmaf(d, d, ssq0);
        d = a01.z - b01.z; ssq0 = fmaf(d, d, ssq0);
        d = a01.w - b01.w; ssq0 = fmaf(d, d, ssq0);
        d = a10.x - b10.x; ssq1 = fmaf(d, d, ssq1);
        d = a10.y - b10.y; ssq1 = fmaf(d, d, ssq1);
        d = a10.z - b10.z; ssq1 = fmaf(d, d, ssq1);
        d = a10.w - b10.w; ssq1 = fmaf(d, d, ssq1);
        d = a11.x - b11.x; ssq1 = fmaf(d, d, ssq1);
        d = a11.y - b11.y; ssq1 = fmaf(d, d, ssq1);
        d = a11.z - b11.z; ssq1 = fmaf(d, d, ssq1);
        d = a11.w - b11.w; ssq1 = fmaf(d, d, ssq1);

        // two interleaved wave-wide reductions
        #pragma unroll
        for (int off = 32; off > 0; off >>= 1) {
            ssq0 += __shfl_xor(ssq0, off);
            ssq1 += __shfl_xor(ssq1, off);
        }

        // lanes 0/1 finish one row each; all-equal <=> ssq == 0 exactly
        if (lane < 2) {
            const int   row = 2 * p + lane;
            const float ssq = lane ? ssq1 : ssq0;
            float dx = sqrtf(ssq + EPS);
            float2 v1 = *reinterpret_cast<const float2*>(y1  + (size_t)row * 2);
            float2 v2 = *reinterpret_cast<const float2*>(y2  + (size_t)row * 2);
            float2 vp = *reinterpret_cast<const float2*>(yp1 + (size_t)row * 2);
            float e0 = v1.x - v2.x, e1 = v1.y - v2.y;
            float dy = sqrtf(fmaf(e0, e0, fmaf(e1, e1, EPS)));
            float w  = (ssq == 0.0f) ? 1.0f : dx;
            float t  = dx - dy;
            float g0 = v1.x - vp.x, g1 = v1.y - vp.y;
            acc += t * t / w + g0 * g0 + g1 * g1;
        }
    }

    #pragma unroll
    for (int off = 32; off > 0; off >>= 1)
        acc += __shfl_xor(acc, off);

    __shared__ float s[BLOCK >> 6];
    if (lane == 0) s[wib] = acc;
    __syncthreads();
    if (threadIdx.x == 0) {
        float t = 0.0f;
        #pragma unroll
        for (int i = 0; i < (BLOCK >> 6); ++i) t += s[i];
        partial[blockIdx.x] = t;
    }
}

__global__ __launch_bounds__(BLOCK) void siamese_final(
    const float* __restrict__ partial, float* __restrict__ out)
{
    // NB = 2048 floats = 512 float4; 256 threads read 2 float4 each.
    const float4* p4 = reinterpret_cast<const float4*>(partial);
    float4 u = p4[threadIdx.x];
    float4 v = p4[threadIdx.x + BLOCK];
    float acc = (u.x + u.y) + (u.z + u.w) + (v.x + v.y) + (v.z + v.w);
    #pragma unroll
    for (int off = 32; off > 0; off >>= 1)
        acc += __shfl_xor(acc, off);
    __shared__ float s[BLOCK >> 6];
    const int lane = threadIdx.x & 63;
    const int wib  = threadIdx.x >> 6;
    if (lane == 0) s[wib] = acc;
    __syncthreads();
    if (threadIdx.x == 0) {
        float t = 0.0f;
        #pragma unroll
        for (int i = 0; i < (BLOCK >> 6); ++i) t += s[i];
        out[0] = t;   // overwrite, never accumulate: safe across graph replays
    }
}

extern "C" void kernel_launch(void* const* d_in, const int* in_sizes, int n_in,
                              void* d_out, int out_size, void* d_ws, size_t ws_size,
                              hipStream_t stream) {
    const float* x1  = (const float*)d_in[0];
    const float* x2  = (const float*)d_in[1];
    const float* y1  = (const float*)d_in[2];
    const float* y2  = (const float*)d_in[3];
    const float* yp1 = (const float*)d_in[4];
    float* out = (float*)d_out;
    float* partial = (float*)d_ws;          // NB floats = 8 KB scratch

    const int B = in_sizes[0] / DH;         // 65536

    siamese_partial<<<NB, BLOCK, 0, stream>>>(x1, x2, y1, y2, yp1, partial, B);
    siamese_final<<<1, BLOCK, 0, stream>>>(partial, out);
}